// Round 1
// baseline (6059.179 us; speedup 1.0000x reference)
//
#include <hip/hip_runtime.h>
#include <math.h>

#define NORI 20
#define NPTS 160
#define CDIM 128
#define TWO_PI_OVER_O (6.28318530717958647692f / 20.0f)

__device__ __forceinline__ float gelu_exact(float x) {
    return 0.5f * x * (1.0f + erff(x * 0.70710678118654752440f));
}

// ---------------------------------------------------------------------------
// fk[l,p,o,c] = (gelu(gelu(poly(cos(th_p - th_o)) @ fw1 + fb1) @ fw2 + fb2)) @ fiber_w[l]
// grid = 2*20*20 = 800 blocks, 128 threads
// ---------------------------------------------------------------------------
__global__ __launch_bounds__(128) void fk_kernel(
    const float* __restrict__ fw1, const float* __restrict__ fb1,
    const float* __restrict__ fw2, const float* __restrict__ fb2,
    const float* __restrict__ fiber_w, float* __restrict__ fk)
{
    __shared__ float s_u[CDIM];
    __shared__ float s_z[CDIM];
    int bid = blockIdx.x;               // l*400 + p*20 + o
    int l = bid / 400;
    int rem = bid % 400;
    int p = rem / 20, o = rem % 20;
    int j = threadIdx.x;

    float t = cosf(TWO_PI_OVER_O * (float)(p - o));
    float f1 = t * t, f2 = f1 * t;

    float u = gelu_exact(t * fw1[j] + f1 * fw1[CDIM + j] + f2 * fw1[2 * CDIM + j] + fb1[j]);
    s_u[j] = u;
    __syncthreads();

    float z0 = 0.f, z1 = 0.f, z2 = 0.f, z3 = 0.f;
    for (int i = 0; i < CDIM; i += 4) {
        z0 += s_u[i    ] * fw2[(i    ) * CDIM + j];
        z1 += s_u[i + 1] * fw2[(i + 1) * CDIM + j];
        z2 += s_u[i + 2] * fw2[(i + 2) * CDIM + j];
        z3 += s_u[i + 3] * fw2[(i + 3) * CDIM + j];
    }
    float z = gelu_exact(((z0 + z1) + (z2 + z3)) + fb2[j]);
    s_z[j] = z;
    __syncthreads();

    const float* fw = fiber_w + l * CDIM * CDIM;
    float a0 = 0.f, a1 = 0.f, a2 = 0.f, a3 = 0.f;
    for (int i = 0; i < CDIM; i += 4) {
        a0 += s_z[i    ] * fw[(i    ) * CDIM + j];
        a1 += s_z[i + 1] * fw[(i + 1) * CDIM + j];
        a2 += s_z[i + 2] * fw[(i + 2) * CDIM + j];
        a3 += s_z[i + 3] * fw[(i + 3) * CDIM + j];
    }
    fk[bid * CDIM + j] = (a0 + a1) + (a2 + a3);
}

// ---------------------------------------------------------------------------
// h0[n,o,c] = sum_i x[n,o,i] * emb_w[i,c]     grid = 3200 rows, 128 threads
// ---------------------------------------------------------------------------
__global__ __launch_bounds__(128) void h0_kernel(
    const float* __restrict__ x, const float* __restrict__ emb_w,
    float* __restrict__ h)
{
    int row = blockIdx.x;   // n*20+o
    int j = threadIdx.x;
    const float* xr = x + row * 16;
    float acc = 0.f;
#pragma unroll
    for (int i = 0; i < 16; ++i) acc += xr[i] * emb_w[i * CDIM + j];
    h[row * CDIM + j] = acc;
}

// ---------------------------------------------------------------------------
// x1[m,o,c] = sum_n  (kb(m,n,o,:) @ Kw)[c] * h[n,o,c]
// kb recomputed in-kernel. grid = 160*20 blocks (one per (m,o)), 256 threads.
// Threads [0,128) handle even n, [128,256) odd n.
// ---------------------------------------------------------------------------
__global__ __launch_bounds__(256) void x1_kernel(
    const float* __restrict__ pos, const float* __restrict__ h,
    const float* __restrict__ bw1, const float* __restrict__ bb1,
    const float* __restrict__ bw2, const float* __restrict__ bb2,
    const float* __restrict__ kw,       // kernel_w + l*128*128
    float* __restrict__ x1)
{
    __shared__ float s_bw2[CDIM * CDIM];
    __shared__ float s_kw[CDIM * CDIM];
    __shared__ float s_bw1[14 * CDIM];
    __shared__ float s_bb1[CDIM];
    __shared__ float s_bb2[CDIM];
    __shared__ float s_buf[2][CDIM];

    int tid = threadIdx.x;
    for (int idx = tid; idx < CDIM * CDIM; idx += 256) {
        s_bw2[idx] = bw2[idx];
        s_kw[idx]  = kw[idx];
    }
    for (int idx = tid; idx < 14 * CDIM; idx += 256) s_bw1[idx] = bw1[idx];
    if (tid < CDIM) { s_bb1[tid] = bb1[tid]; s_bb2[tid] = bb2[tid]; }

    int m = blockIdx.x / NORI;
    int o = blockIdx.x % NORI;
    float th = TWO_PI_OVER_O * (float)o;
    float ox = cosf(th), oy = sinf(th);
    float pmx = pos[2 * m], pmy = pos[2 * m + 1];

    int half = tid >> 7;
    int j = tid & (CDIM - 1);
    float acc = 0.f;
    __syncthreads();

    for (int it = 0; it < NPTS / 2; ++it) {
        int n = 2 * it + half;
        float rx = pos[2 * n] - pmx, ry = pos[2 * n + 1] - pmy;
        float a = rx * ox + ry * oy;                 // inv1
        float rn = sqrtf(rx * rx + ry * ry);
        float b = rn * fabsf(1.f - a);               // inv2 = ||rel*(1-inv1)||

        float p[14];
        p[0] = a; p[1] = b;
        p[2] = a * a; p[3] = a * b; p[4] = b * a; p[5] = b * b;
        p[6] = p[2] * a; p[7] = p[2] * b; p[8] = p[3] * a; p[9] = p[3] * b;
        p[10] = p[4] * a; p[11] = p[4] * b; p[12] = p[5] * a; p[13] = p[5] * b;

        float u = s_bb1[j];
#pragma unroll
        for (int i = 0; i < 14; ++i) u += p[i] * s_bw1[i * CDIM + j];
        u = gelu_exact(u);
        s_buf[half][j] = u;
        __syncthreads();

        float z0 = 0.f, z1 = 0.f, z2 = 0.f, z3 = 0.f;
        for (int i = 0; i < CDIM; i += 4) {
            z0 += s_buf[half][i    ] * s_bw2[(i    ) * CDIM + j];
            z1 += s_buf[half][i + 1] * s_bw2[(i + 1) * CDIM + j];
            z2 += s_buf[half][i + 2] * s_bw2[(i + 2) * CDIM + j];
            z3 += s_buf[half][i + 3] * s_bw2[(i + 3) * CDIM + j];
        }
        float z = gelu_exact(((z0 + z1) + (z2 + z3)) + s_bb2[j]);
        __syncthreads();                 // all reads of u done
        s_buf[half][j] = z;
        __syncthreads();                 // z visible

        float k0 = 0.f, k1 = 0.f, k2 = 0.f, k3 = 0.f;
        for (int i = 0; i < CDIM; i += 4) {
            k0 += s_buf[half][i    ] * s_kw[(i    ) * CDIM + j];
            k1 += s_buf[half][i + 1] * s_kw[(i + 1) * CDIM + j];
            k2 += s_buf[half][i + 2] * s_kw[(i + 2) * CDIM + j];
            k3 += s_buf[half][i + 3] * s_kw[(i + 3) * CDIM + j];
        }
        float kern = (k0 + k1) + (k2 + k3);
        acc += kern * h[(n * NORI + o) * CDIM + j];
        __syncthreads();                 // before next iter overwrites s_buf
    }

    // combine the two halves
    s_buf[half][j] = acc;
    __syncthreads();
    if (half == 0)
        x1[(m * NORI + o) * CDIM + j] = s_buf[0][j] + s_buf[1][j];
}

// ---------------------------------------------------------------------------
// per (m,p): x2 = (sum_o x1[m,o,:] * fk[p,o,:]) / C + conv_b ; LayerNorm ;
// mid = gelu(xn @ w1 + b1) ; h[m,p,:] += mid @ w2 + b2
// grid = 3200 blocks, 128 threads
// ---------------------------------------------------------------------------
__global__ __launch_bounds__(128) void mlp_kernel(
    const float* __restrict__ x1, const float* __restrict__ fk_l,
    const float* __restrict__ conv_b, const float* __restrict__ ln_g,
    const float* __restrict__ ln_b,
    const float* __restrict__ w1, const float* __restrict__ b1,
    const float* __restrict__ w2, const float* __restrict__ b2,
    float* __restrict__ h)
{
    __shared__ float s_xn[CDIM];
    __shared__ float s_mid[4 * CDIM];
    __shared__ float s_red[4];

    int m = blockIdx.x / NORI;
    int p = blockIdx.x % NORI;
    int c = threadIdx.x;

    float x2 = 0.f;
#pragma unroll
    for (int o = 0; o < NORI; ++o)
        x2 += x1[(m * NORI + o) * CDIM + c] * fk_l[(p * NORI + o) * CDIM + c];
    x2 = x2 * (1.0f / (float)CDIM) + conv_b[c];

    // LayerNorm over c (128 values, 2 waves)
    float s1 = x2, sq = x2 * x2;
    for (int off = 32; off; off >>= 1) {
        s1 += __shfl_down(s1, off, 64);
        sq += __shfl_down(sq, off, 64);
    }
    if ((c & 63) == 0) { s_red[c >> 6] = s1; s_red[2 + (c >> 6)] = sq; }
    __syncthreads();
    float mu  = (s_red[0] + s_red[1]) * (1.0f / (float)CDIM);
    float var = (s_red[2] + s_red[3]) * (1.0f / (float)CDIM) - mu * mu;
    float xn = (x2 - mu) * rsqrtf(var + 1e-5f) * ln_g[c] + ln_b[c];
    s_xn[c] = xn;
    __syncthreads();

#pragma unroll
    for (int q = 0; q < 4; ++q) {
        int k = q * CDIM + c;
        float a0 = 0.f, a1 = 0.f, a2 = 0.f, a3 = 0.f;
        for (int i = 0; i < CDIM; i += 4) {
            a0 += s_xn[i    ] * w1[(i    ) * 512 + k];
            a1 += s_xn[i + 1] * w1[(i + 1) * 512 + k];
            a2 += s_xn[i + 2] * w1[(i + 2) * 512 + k];
            a3 += s_xn[i + 3] * w1[(i + 3) * 512 + k];
        }
        s_mid[k] = gelu_exact(((a0 + a1) + (a2 + a3)) + b1[k]);
    }
    __syncthreads();

    float o0 = 0.f, o1 = 0.f, o2 = 0.f, o3 = 0.f;
    for (int k = 0; k < 512; k += 4) {
        o0 += s_mid[k    ] * w2[(k    ) * CDIM + c];
        o1 += s_mid[k + 1] * w2[(k + 1) * CDIM + c];
        o2 += s_mid[k + 2] * w2[(k + 2) * CDIM + c];
        o3 += s_mid[k + 3] * w2[(k + 3) * CDIM + c];
    }
    float out = ((o0 + o1) + (o2 + o3)) + b2[c];
    h[(m * NORI + p) * CDIM + c] += out;
}

// ---------------------------------------------------------------------------
extern "C" void kernel_launch(void* const* d_in, const int* in_sizes, int n_in,
                              void* d_out, int out_size, void* d_ws, size_t ws_size,
                              hipStream_t stream)
{
    const float* x        = (const float*)d_in[0];
    const float* pos      = (const float*)d_in[1];
    const float* bw1      = (const float*)d_in[2];
    const float* bb1      = (const float*)d_in[3];
    const float* bw2      = (const float*)d_in[4];
    const float* bb2      = (const float*)d_in[5];
    const float* fw1      = (const float*)d_in[6];
    const float* fb1      = (const float*)d_in[7];
    const float* fw2      = (const float*)d_in[8];
    const float* fb2      = (const float*)d_in[9];
    const float* emb_w    = (const float*)d_in[10];
    const float* kernel_w = (const float*)d_in[11];
    const float* fiber_w  = (const float*)d_in[12];
    const float* conv_b   = (const float*)d_in[13];
    const float* ln_g     = (const float*)d_in[14];
    const float* ln_b     = (const float*)d_in[15];
    const float* mlp_w1   = (const float*)d_in[16];
    const float* mlp_b1   = (const float*)d_in[17];
    const float* mlp_w2   = (const float*)d_in[18];
    const float* mlp_b2   = (const float*)d_in[19];

    float* h  = (float*)d_out;          // [160,20,128]
    float* ws = (float*)d_ws;
    float* fk = ws;                     // [2,20,20,128] = 102400 floats
    float* x1 = ws + 2 * NORI * NORI * CDIM;   // [160,20,128] = 409600 floats

    fk_kernel<<<2 * NORI * NORI, 128, 0, stream>>>(fw1, fb1, fw2, fb2, fiber_w, fk);
    h0_kernel<<<NPTS * NORI, 128, 0, stream>>>(x, emb_w, h);

    for (int l = 0; l < 2; ++l) {
        x1_kernel<<<NPTS * NORI, 256, 0, stream>>>(
            pos, h, bw1, bb1, bw2, bb2, kernel_w + l * CDIM * CDIM, x1);
        mlp_kernel<<<NPTS * NORI, 128, 0, stream>>>(
            x1, fk + l * NORI * NORI * CDIM,
            conv_b + l * CDIM, ln_g + l * CDIM, ln_b + l * CDIM,
            mlp_w1 + l * CDIM * 4 * CDIM, mlp_b1 + l * 4 * CDIM,
            mlp_w2 + l * 4 * CDIM * CDIM, mlp_b2 + l * CDIM, h);
    }
}